// Round 7
// baseline (276.250 us; speedup 1.0000x reference)
//
#include <hip/hip_runtime.h>
#include <math.h>

#define WH     256
#define NDEPTH 8
#define NBATCH 1024
#define NB     16           // batch elements per block (256 blocks, 1/CU)
#define PLANE  (WH * WH)    // 65536

typedef _Float16 h2 __attribute__((ext_vector_type(2)));

// ws layout (fp16): wsh[arr][hq8][d][hs][w]
//   arr: 0=M1 1=B1 2=M2 3=B2 ; hq8 = h>>5 ; hs = h&31 ; w inner (WIDTH)
// Exchange mailbox: 256 blocks x 16 slots of uint64 at ws + 6 MiB
// (ws >= 8 MiB, verified R2). Zeroed by transpose every launch; prop only
// ever writes monotone epochs -> no read-clear needed.
#define SLAB   (32 * WH)              // halfs per (arr,hq8,d) slab = 8192
#define HQ8BLK (NDEPTH * SLAB)        // halfs per (arr,hq8) block = 65536
#define XBUF_OFF (6u * 1024u * 1024u) // byte offset of mailbox in d_ws

// ---------------------------------------------------------------------------
// Transpose + fp32->fp16 convert. 512 blocks x 256 threads. (~10us)
// Blocks 0..255 also zero the exchange mailbox (stream-ordered before prop).
// ---------------------------------------------------------------------------
__global__ __launch_bounds__(256) void transpose_half_k(const float* __restrict__ M1,
                                                        const float* __restrict__ B1,
                                                        const float* __restrict__ M2,
                                                        const float* __restrict__ B2,
                                                        _Float16* __restrict__ wsh,
                                                        unsigned long long* __restrict__ xbuf) {
    __shared__ float tile[64][65];
    const int bid = blockIdx.x;

    if (bid < 256 && threadIdx.x < NB)          // zero mailbox for this launch
        xbuf[bid * NB + threadIdx.x] = 0ULL;

    const int arr = bid >> 7;
    const int d   = (bid >> 4) & 7;
    const int ht  = (bid >> 2) & 3;     // h-tile (64 rows) = 2 hq8 subsets
    const int wt  = bid & 3;            // w-tile

    const float* src = (arr == 0) ? M1 : (arr == 1) ? B1 : (arr == 2) ? M2 : B2;
    const float* s = src + d * PLANE;
    _Float16* ob = wsh + (size_t)((arr * 8 + ht * 2) * NDEPTH + d) * SLAB;

    const int t   = threadIdx.x;
    const int q16 = t >> 4;     // 0..15
    const int r16 = t & 15;     // 0..15

#pragma unroll
    for (int p = 0; p < 4; ++p) {        // read: float4 along h ([d][w][h])
        const int wrow = q16 + p * 16;
        const float4 v = *(const float4*)(s + (wt * 64 + wrow) * WH + ht * 64 + r16 * 4);
        tile[wrow][r16 * 4 + 0] = v.x;
        tile[wrow][r16 * 4 + 1] = v.y;
        tile[wrow][r16 * 4 + 2] = v.z;
        tile[wrow][r16 * 4 + 3] = v.w;
    }
    __syncthreads();
#pragma unroll
    for (int p = 0; p < 4; ++p) {        // write: 4 halfs along w
        const int hrow = q16 + p * 16;   // local h 0..63 (tile column)
        const int sub  = p >> 1;         // hrow>>5: which hq8 of this tile
        const int hs   = q16 + (p & 1) * 16;   // hrow & 31
        const int wl   = r16 * 4;
        union { _Float16 f[4]; uint2 u; } pk;
        pk.f[0] = (_Float16)tile[wl + 0][hrow];
        pk.f[1] = (_Float16)tile[wl + 1][hrow];
        pk.f[2] = (_Float16)tile[wl + 2][hrow];
        pk.f[3] = (_Float16)tile[wl + 3][hrow];
        *(uint2*)(ob + (size_t)sub * HQ8BLK + hs * WH + wt * 64 + wl) = pk.u;
    }
}

// ---------------------------------------------------------------------------
// Prop: 256 blocks x 512 threads, NB=16, W-split pairs, 16B loads.
// *** R11-R16 lore: perf is pinned by VECTOR-LOAD INSTRUCTION COUNT per CU
// *** (~60 cy each): R0-R5 all 2048 loads/CU -> 51-62us regardless of
// *** schedule; R6 halved BYTES but kept 2048 (8B) loads -> no gain, and
// *** device-scope atomicExch exchange went to L3/mem (WRITE_SIZE 642KB)
// *** -> +13us. Even peak GEMMs (m97/m201/HK) sit at 17-23 B/cy/CU = the
// *** same ~60cy/load rate. Only fewer 16B loads help.
// *** R17: W-split with dwordx4 loads: 1024 loads/CU (2x cut). NB=16 ->
// *** 512cy math/chunk > L2 latency -> 2-wave interleave hides it (plain
// *** loads, no asm). Exchange: release/acquire agent-scope store/load with
// *** monotone epochs (no RMW, no clearing; transpose zeroes per launch).
// Floors: math 13.7us, loads 1024x60cy ~26us -> target 22-30us.
// ---------------------------------------------------------------------------
__global__ __launch_bounds__(512, 2) void prop_h_k(const _Float16* __restrict__ wsh,
                                                   const float* __restrict__ val,
                                                   float* __restrict__ out,
                                                   unsigned long long* __restrict__ xbuf) {
    const int bid  = blockIdx.x;
    const int x    = bid & 7;             // XCD id (dispatch round-robin)
    const int br   = x >> 2;              // branch -> XCD half
    const int wh   = (bid >> 3) & 1;      // W-half (partner = bid^8, same XCD)
    const int bg   = (bid >> 4) * 4 + (x & 3);   // batch group 0..63
    const int t    = threadIdx.x;
    const int wave = t >> 6;              // 0..7 = hq8 subset
    const int lane = t & 63;
    const int cls  = lane >> 4;           // row class 0..3
    const int j16  = lane & 15;           // w-slice within half-row

    const int arrM = br ? 2 : 0;
    const int arrB = br ? 3 : 1;
    // uint4 units: HQ8BLK/8 = 8192 per (arr,hq8); row = 32 uint4 (256 halfs);
    // W-half = 16 uint4. Lane map: row cls (4 rows/load), 16B w-slice j16.
    // Chunk = 8 rows = 2 loads (offset 0 and 128 = 4 rows); advance +256.
    // 4 chunks/depth consume the 32-row slab; stream continuous across d.
    const uint4* __restrict__ mp = (const uint4*)wsh + (size_t)(arrM * 8 + wave) * (HQ8BLK / 8)
                                   + cls * 32 + wh * 16 + j16;
    const uint4* __restrict__ bp = (const uint4*)wsh + (size_t)(arrB * 8 + wave) * (HQ8BLK / 8)
                                   + cls * 32 + wh * 16 + j16;

    __shared__ uint4 part[8][NB][16];   // 32 KB: [wave][nb][w-slice]
    __shared__ float qs[NB];            // combined q per depth

    h2 q2[NB];
#pragma unroll
    for (int nb = 0; nb < NB; ++nb) {
        const _Float16 qh = (_Float16)val[bg * NB + nb];   // block-uniform
        q2[nb].x = qh; q2[nb].y = qh;
    }

    union H8 { uint4 u; h2 h[4]; };
    union IH { int i; h2 h; };
    union { unsigned short us; _Float16 f; } ninf; ninf.us = 0xFC00;  // -inf
    h2 NEGINF; NEGINF.x = ninf.f; NEGINF.y = ninf.f;

    unsigned long long* xmine = xbuf + bid * NB;
    unsigned long long* xpart = xbuf + (bid ^ 8) * NB;

    for (int d = 0; d < NDEPTH; ++d) {
        h2 acc[NB][4];
#pragma unroll
        for (int nb = 0; nb < NB; ++nb)
#pragma unroll
            for (int k = 0; k < 4; ++k) acc[nb][k] = NEGINF;

#pragma unroll
        for (int c = 0; c < 4; ++c) {        // 4 chunks x 8 rows = 32 rows/depth
            H8 m0, m1, b0, b1;
            m0.u = mp[0]; m1.u = mp[128];    // rows cls and cls+4 of this chunk
            b0.u = bp[0]; b1.u = bp[128];
            mp += 256; bp += 256;
#pragma unroll
            for (int nb = 0; nb < NB; ++nb) {
                const h2 qq = q2[nb];
#pragma unroll
                for (int k = 0; k < 4; ++k) {
                    acc[nb][k] = __builtin_elementwise_max(
                        acc[nb][k], __builtin_elementwise_fma(qq, m0.h[k], b0.h[k]));
                    acc[nb][k] = __builtin_elementwise_max(
                        acc[nb][k], __builtin_elementwise_fma(qq, m1.h[k], b1.h[k]));
                }
            }
        }

        // combine the 4 row-classes (same w-slice j16): xor16 then xor32 max
        // -> every lane holds max over all 32 slab rows for its 8-W slice.
#pragma unroll
        for (int nb = 0; nb < NB; ++nb)
#pragma unroll
            for (int k = 0; k < 4; ++k) {
                IH a, o1, o2;
                a.h = acc[nb][k];
                o1.i = __shfl_xor(a.i, 16);
                a.h = __builtin_elementwise_max(a.h, o1.h);
                o2.i = __shfl_xor(a.i, 32);
                acc[nb][k] = __builtin_elementwise_max(a.h, o2.h);
            }

        // stage: class cls stores nb = cls*4..cls*4+3 (compile-time source
        // index, runtime predicate -> no scratch; rule #20).
#pragma unroll
        for (int nb = 0; nb < NB; ++nb) {
            if (cls == (nb >> 2)) {
                H8 st;
                st.h[0] = acc[nb][0]; st.h[1] = acc[nb][1];
                st.h[2] = acc[nb][2]; st.h[3] = acc[nb][3];
                part[wave][nb][j16] = st.u;
            }
        }
        __syncthreads();

        // reduce: t<256, nb = t>>4, j = t&15. Max over 8 waves (all 256 H),
        // min over 8 halfs + 16 slices (this block's 128 W) -> scalar r.
        if (t < 256) {
            const int nb = t >> 4;
            const int j  = t & 15;
            H8 v; v.u = part[0][nb][j];
#pragma unroll
            for (int s2 = 1; s2 < 8; ++s2) {
                H8 w2; w2.u = part[s2][nb][j];
#pragma unroll
                for (int k = 0; k < 4; ++k)
                    v.h[k] = __builtin_elementwise_max(v.h[k], w2.h[k]);
            }
            h2 mn = __builtin_elementwise_min(
                        __builtin_elementwise_min(v.h[0], v.h[1]),
                        __builtin_elementwise_min(v.h[2], v.h[3]));
            float r = fminf((float)mn.x, (float)mn.y);
#pragma unroll
            for (int off = 8; off > 0; off >>= 1)
                r = fminf(r, __shfl_xor(r, off, 16));   // min within 16-lane group

            // exchange W-half partial with partner block (j==0 holds r):
            // monotone-epoch release/acquire; no RMW, no clearing.
            if (j == 0) {
                union { float f; unsigned u; } pv; pv.f = r;
                __hip_atomic_store(&xmine[nb],
                                   ((unsigned long long)pv.u << 32) | (unsigned)(d + 1),
                                   __ATOMIC_RELEASE, __HIP_MEMORY_SCOPE_AGENT);
                unsigned long long got;
                for (;;) {
                    got = __hip_atomic_load(&xpart[nb], __ATOMIC_ACQUIRE,
                                            __HIP_MEMORY_SCOPE_AGENT);
                    if ((unsigned)(got & 0xFFFFFFFFULL) == (unsigned)(d + 1)) break;
                    __builtin_amdgcn_s_sleep(1);
                }
                union { unsigned u; float f; } qv; qv.u = (unsigned)(got >> 32);
                qs[nb] = fminf(r, qv.f);
            }
        }
        __syncthreads();
#pragma unroll
        for (int nb = 0; nb < NB; ++nb) {
            const _Float16 qh = (_Float16)qs[nb];
            q2[nb].x = qh; q2[nb].y = qh;
        }
        // part[] rewritten only after next depth's math -> safe w.r.t. readers
    }

    if (wh == 0 && t < NB) out[br * NBATCH + bg * NB + t] = qs[t];
}

// ---------------------------------------------------------------------------
extern "C" void kernel_launch(void* const* d_in, const int* in_sizes, int n_in,
                              void* d_out, int out_size, void* d_ws, size_t ws_size,
                              hipStream_t stream) {
    const float* val = (const float*)d_in[0];
    const float* M1  = (const float*)d_in[1];
    const float* B1  = (const float*)d_in[2];
    const float* M2  = (const float*)d_in[3];
    const float* B2  = (const float*)d_in[4];
    float*    out = (float*)d_out;
    _Float16* wsh = (_Float16*)d_ws;   // 4 MiB data (ws >= 8 MiB, R2)
    unsigned long long* xbuf =
        (unsigned long long*)((char*)d_ws + XBUF_OFF);   // 32 KB mailbox

    transpose_half_k<<<dim3(512), dim3(256), 0, stream>>>(M1, B1, M2, B2, wsh, xbuf);
    prop_h_k<<<dim3(256), dim3(512), 0, stream>>>(wsh, val, out, xbuf);
}

// Round 8
// 117.712 us; speedup vs baseline: 2.3468x; 2.3468x over previous
//
#include <hip/hip_runtime.h>
#include <math.h>

#define WH     256
#define NDEPTH 8
#define NBATCH 1024
#define NB     8            // batch elements per block (256 blocks, 1/CU)
#define PLANE  (WH * WH)    // 65536

typedef _Float16 h2 __attribute__((ext_vector_type(2)));

// ws layout (fp16): wsh[arr][hq8][d][hs][w]
//   arr: 0=M1 1=B1 2=M2 3=B2 ; hq8 = h>>5 ; hs = h&31 ; w inner (WIDTH)
#define SLAB   (32 * WH)              // halfs per (arr,hq8,d) slab = 8192
#define HQ8BLK (NDEPTH * SLAB)        // halfs per (arr,hq8) block = 65536

// ---------------------------------------------------------------------------
// Transpose + fp32->fp16 convert. 512 blocks x 256 threads. (~10us)
// ---------------------------------------------------------------------------
__global__ __launch_bounds__(256) void transpose_half_k(const float* __restrict__ M1,
                                                        const float* __restrict__ B1,
                                                        const float* __restrict__ M2,
                                                        const float* __restrict__ B2,
                                                        _Float16* __restrict__ wsh) {
    __shared__ float tile[64][65];
    const int bid = blockIdx.x;
    const int arr = bid >> 7;
    const int d   = (bid >> 4) & 7;
    const int ht  = (bid >> 2) & 3;     // h-tile (64 rows) = 2 hq8 subsets
    const int wt  = bid & 3;            // w-tile

    const float* src = (arr == 0) ? M1 : (arr == 1) ? B1 : (arr == 2) ? M2 : B2;
    const float* s = src + d * PLANE;
    _Float16* ob = wsh + (size_t)((arr * 8 + ht * 2) * NDEPTH + d) * SLAB;

    const int t   = threadIdx.x;
    const int q16 = t >> 4;     // 0..15
    const int r16 = t & 15;     // 0..15

#pragma unroll
    for (int p = 0; p < 4; ++p) {        // read: float4 along h ([d][w][h])
        const int wrow = q16 + p * 16;
        const float4 v = *(const float4*)(s + (wt * 64 + wrow) * WH + ht * 64 + r16 * 4);
        tile[wrow][r16 * 4 + 0] = v.x;
        tile[wrow][r16 * 4 + 1] = v.y;
        tile[wrow][r16 * 4 + 2] = v.z;
        tile[wrow][r16 * 4 + 3] = v.w;
    }
    __syncthreads();
#pragma unroll
    for (int p = 0; p < 4; ++p) {        // write: 4 halfs along w
        const int hrow = q16 + p * 16;   // local h 0..63 (tile column)
        const int sub  = p >> 1;         // hrow>>5: which hq8 of this tile
        const int hs   = q16 + (p & 1) * 16;   // hrow & 31
        const int wl   = r16 * 4;
        union { _Float16 f[4]; uint2 u; } pk;
        pk.f[0] = (_Float16)tile[wl + 0][hrow];
        pk.f[1] = (_Float16)tile[wl + 1][hrow];
        pk.f[2] = (_Float16)tile[wl + 2][hrow];
        pk.f[3] = (_Float16)tile[wl + 3][hrow];
        *(uint2*)(ob + (size_t)sub * HQ8BLK + hs * WH + wt * 64 + wl) = pk.u;
    }
}

// ---------------------------------------------------------------------------
// Prop: 256 blocks x 512 threads (8 waves = 2 waves/SIMD), NB=8.
// *** R11-R17 lore: perf is pinned at ~17 B/cy/CU L2->L1 FILL regardless of
// *** schedule, load width, occupancy, rings, glds (R0-R5: 51-66us; R6:
// *** same bytes, 2x insts, same time -> BYTES-capped, not inst-capped).
// *** Inter-block exchange (R6 atomicExch +13us; R7 rel/acq agent-scope
// *** +165us!) is ruled out: agent scope = MALL coherence on 8-XCD chip.
// *** R18 theory: the fill cap is L2 BANK CONTENTION - all 32 CUs of an XCD
// *** stream the SAME 2MB in the SAME order in lockstep (no L2 multicast ->
// *** same-line requests serialize). Fix: DECORRELATE. max-reduce is
// *** associative -> chunk order is free. Rotate wave->slab by g=(bid>>3)
// *** (block-within-XCD) and chunk-within-slab by g>>3: 32 blocks touch 32
// *** distinct 2KB regions at any instant. Pure permutation: no sync, no
// *** extra traffic, no correctness dependence on XCD mapping (G16-safe).
// Floors: math 13.7us; fill 2MB @30-50 B/cy -> 10-17us. Target 25-35us.
// ---------------------------------------------------------------------------
__global__ __launch_bounds__(512) void prop_h_k(const _Float16* __restrict__ wsh,
                                                const float* __restrict__ val,
                                                float* __restrict__ out) {
    const int bid  = blockIdx.x;
    const int x    = bid & 7;             // XCD hint (dispatch round-robin)
    const int br   = x >> 2;              // branch -> XCD half
    const int g    = bid >> 3;            // block index within XCD, 0..31
    const int bg   = g * 4 + (x & 3);     // batch group 0..127
    const int t    = threadIdx.x;
    const int wave = t >> 6;              // physical wave 0..7
    const int lane = t & 63;

    const int slab = (wave + g) & 7;      // rotated hq8 slab assignment
    const int crot = (g >> 3) & 7;        // chunk rotation phase 0..3

    const int arrM = br ? 2 : 0;
    const int arrB = br ? 3 : 1;
    // uint4 units: HQ8BLK/8 = 8192 per (arr,hq8) = 1024/depth; chunk = 128
    // uint4 (4 rows); lane covers rows 0-1 (mp[0]) / rows 2-3 (mp[64]).
    const uint4* __restrict__ mpS = (const uint4*)wsh + (size_t)(arrM * 8 + slab) * (HQ8BLK / 8) + lane;
    const uint4* __restrict__ bpS = (const uint4*)wsh + (size_t)(arrB * 8 + slab) * (HQ8BLK / 8) + lane;

    h2 q2[NB];
#pragma unroll
    for (int nb = 0; nb < NB; ++nb) {
        const _Float16 qh = (_Float16)val[bg * NB + nb];   // block-uniform
        q2[nb].x = qh; q2[nb].y = qh;
    }

    __shared__ h2 part[8][NB][128];   // 32 KB: [wave][nb][w/2]
    __shared__ float qs[NB];

    union H8 { uint4 u; h2 h[4]; };
    union IH { int i; h2 h; };
    union { unsigned short us; _Float16 f; } ninf; ninf.us = 0xFC00;  // -inf
    h2 NEGINF; NEGINF.x = ninf.f; NEGINF.y = ninf.f;

    for (int d = 0; d < NDEPTH; ++d) {
        h2 acc[NB][4];
#pragma unroll
        for (int nb = 0; nb < NB; ++nb)
#pragma unroll
            for (int k = 0; k < 4; ++k) acc[nb][k] = NEGINF;

#pragma unroll
        for (int c = 0; c < 8; ++c) {        // 8 chunks x 4 rows, ROTATED order
            const int ci = (c + crot) & 7;   // scalar-uniform rotation
            const uint4* m = mpS + ci * 128;
            const uint4* b = bpS + ci * 128;
            H8 m0, m1, b0, b1;
            m0.u = m[0]; m1.u = m[64];
            b0.u = b[0]; b1.u = b[64];
#pragma unroll
            for (int nb = 0; nb < NB; ++nb) {
                const h2 qq = q2[nb];
#pragma unroll
                for (int k = 0; k < 4; ++k) {
                    acc[nb][k] = __builtin_elementwise_max(
                        acc[nb][k], __builtin_elementwise_fma(qq, m0.h[k], b0.h[k]));
                    acc[nb][k] = __builtin_elementwise_max(
                        acc[nb][k], __builtin_elementwise_fma(qq, m1.h[k], b1.h[k]));
                }
            }
        }
        mpS += 1024; bpS += 1024;            // next depth slab

        // combine lane-halves: lane l and l+32 hold adjacent rows at the same
        // w-slice -> one xor-32 max.
#pragma unroll
        for (int nb = 0; nb < NB; ++nb)
#pragma unroll
            for (int k = 0; k < 4; ++k) {
                IH a; a.h = acc[nb][k];
                IH o2; o2.i = __shfl_xor(a.i, 32);
                acc[nb][k] = __builtin_elementwise_max(acc[nb][k], o2.h);
            }

        // stage partials: one slot per physical wave (its rotated slab is
        // still a disjoint 32-row subset; reduce maxes over all slots).
        if (lane < 32) {
#pragma unroll
            for (int nb = 0; nb < NB; ++nb) {
                H8 st;
                st.h[0] = acc[nb][0]; st.h[1] = acc[nb][1];
                st.h[2] = acc[nb][2]; st.h[3] = acc[nb][3];
                *(uint4*)&part[wave][nb][lane * 4] = st.u;
            }
        }
        __syncthreads();

        // reduce: thread t -> nb = t>>5 (0..7), j = t&31 (w block j*8..+7)
        if (t < 256) {
            const int nb = t >> 5;
            const int j  = t & 31;
            H8 v; v.u = *(const uint4*)&part[0][nb][j * 4];
#pragma unroll
            for (int s2 = 1; s2 < 8; ++s2) {
                H8 w2; w2.u = *(const uint4*)&part[s2][nb][j * 4];
#pragma unroll
                for (int k = 0; k < 4; ++k)
                    v.h[k] = __builtin_elementwise_max(v.h[k], w2.h[k]);
            }
            h2 mn = __builtin_elementwise_min(
                        __builtin_elementwise_min(v.h[0], v.h[1]),
                        __builtin_elementwise_min(v.h[2], v.h[3]));
            float r = fminf((float)mn.x, (float)mn.y);
#pragma unroll
            for (int off = 16; off > 0; off >>= 1)
                r = fminf(r, __shfl_xor(r, off, 32));   // min within 32-lane group
            if (j == 0) qs[nb] = r;
        }
        __syncthreads();
#pragma unroll
        for (int nb = 0; nb < NB; ++nb) {
            const _Float16 qh = (_Float16)qs[nb];
            q2[nb].x = qh; q2[nb].y = qh;
        }
        // part[] rewritten only after this barrier next depth -> safe
    }

    if (t < NB) out[br * NBATCH + bg * NB + t] = qs[t];
}

// ---------------------------------------------------------------------------
extern "C" void kernel_launch(void* const* d_in, const int* in_sizes, int n_in,
                              void* d_out, int out_size, void* d_ws, size_t ws_size,
                              hipStream_t stream) {
    const float* val = (const float*)d_in[0];
    const float* M1  = (const float*)d_in[1];
    const float* B1  = (const float*)d_in[2];
    const float* M2  = (const float*)d_in[3];
    const float* B2  = (const float*)d_in[4];
    float*    out = (float*)d_out;
    _Float16* wsh = (_Float16*)d_ws;   // 4 MiB (ws >= 8 MiB, R2)

    transpose_half_k<<<dim3(512), dim3(256), 0, stream>>>(M1, B1, M2, B2, wsh);
    prop_h_k<<<dim3(256), dim3(512), 0, stream>>>(wsh, val, out);
}